// Round 1
// baseline (2924.522 us; speedup 1.0000x reference)
//
#include <hip/hip_runtime.h>
#include <hip/hip_bf16.h>
#include <math.h>

#define BS   4096
#define ZD   512
#define HIDN 1024
#define ZINN 128
#define NST  32
#define NP   3072   // 3*HIDN, gate-interleaved column space (96 = 3x32 groups)

typedef unsigned short u16;
typedef __bf16 bf16x8 __attribute__((ext_vector_type(8)));
typedef float f32x4 __attribute__((ext_vector_type(4)));
typedef float f32x16 __attribute__((ext_vector_type(16)));

static __device__ __forceinline__ u16 bf_bits(float v) {
  __bf16 b = (__bf16)v;
  return __builtin_bit_cast(unsigned short, b);
}
static __device__ __forceinline__ float bf_val(float v) {
  return (float)(__bf16)v;
}

// async global -> LDS, 16 bytes per lane. LDS dest = wave-uniform base + lane*16.
static __device__ __forceinline__ void ld_lds16(const u16* g, u16* l) {
  __builtin_amdgcn_global_load_lds(
      (const __attribute__((address_space(1))) void*)g,
      (__attribute__((address_space(3))) void*)l, 16, 0, 0);
}

// W' row w -> original W_hh/W_ih row. NEW 32-granular interleave for 32x32 MFMA:
// w = g*96 + j*32 + m  ->  j*1024 + g*32 + m   (j = gate r/u/n, m = h-col within group)
static __device__ __forceinline__ int r_orig(int w) {
  const int g = w / 96;
  const int rem = w - g * 96;
  const int j = rem >> 5, m = rem & 31;
  return j * 1024 + g * 32 + m;
}

// ---------------- packed split layout ----------------
// Pk[row][2048 u16]: 32 K-tiles x 64 u16. Within tile: 8 chunks of 8 u16;
// chunk c = 2*kc + islo (kc = (k>>3)&3) stored at slot p = c ^ (row&7).
// -> staging is LINEAR global_load_lds; ds_read_b128 is bank-conflict-free.
static __device__ __forceinline__ void pack_write(u16* __restrict__ P, int row, int col, float v) {
  const int kt = col >> 5, kc = (col >> 3) & 3, e = col & 7, rx = row & 7;
  const size_t base = ((size_t)row << 11) + kt * 64;
  const float h = bf_val(v);
  P[base + (((kc << 1) ^ rx) << 3) + e] = bf_bits(v);
  P[base + ((((kc << 1) | 1) ^ rx) << 3) + e] = bf_bits(v - h);
}

// ---------------- prep kernels ----------------

__global__ void k_split(const float* __restrict__ s, u16* __restrict__ hi,
                        u16* __restrict__ lo, int n) {
  int i = blockIdx.x * 256 + threadIdx.x;
  if (i >= n) return;
  float v = s[i];
  float h = bf_val(v);
  hi[i] = bf_bits(v);
  lo[i] = bf_bits(v - h);
}

// W_hh -> packed/swizzled Bpk with gate-interleaved row reorder
__global__ void k_pack_whh(const float* __restrict__ W_hh, u16* __restrict__ Bpk) {
  int i = blockIdx.x * 256 + threadIdx.x;
  if (i >= NP * HIDN) return;
  const int w = i >> 10, k = i & 1023;
  const float v = W_hh[(size_t)r_orig(w) * HIDN + k];
  pack_write(Bpk, w, k, v);
}

// W_ih[:,3:131] -> split (reordered rows); W_ih[:,0:3] -> wtok (reordered); cb0 (reordered)
__global__ void k_prep_wih(const float* __restrict__ W_ih, const float* __restrict__ b_ih,
                           const float* __restrict__ b_hh,
                           u16* __restrict__ whi, u16* __restrict__ wlo,
                           float* __restrict__ wtok, float* __restrict__ cb0) {
  int i = blockIdx.x * 256 + threadIdx.x;
  if (i < NP * 128) {
    const int w = i >> 7, c = i & 127;
    const int r = r_orig(w);
    const float v = W_ih[r * 131 + 3 + c];
    const float h = bf_val(v);
    whi[i] = bf_bits(v);
    wlo[i] = bf_bits(v - h);
  }
  if (i < NP * 3) {
    const int w = i / 3, s = i - w * 3;
    wtok[i] = W_ih[r_orig(w) * 131 + s];
  }
  if (i < NP) {
    const int r = r_orig(i);
    cb0[i] = b_ih[r] + (r < 2048 ? b_hh[r] : 0.0f);
  }
}

__global__ void k_token_init(const float* __restrict__ init_input, float* __restrict__ token) {
  int i = blockIdx.x * 256 + threadIdx.x;
  if (i < BS * 4) token[i] = ((i & 3) < 3) ? init_input[i & 3] : 0.0f;
}

// ---------------- generic split-3 GEMM (prep only): C = A*B^T (+bias) ----------------
// OUTMODE: 0 = f32 only, 1 = f32 + plain hi/lo splits, 2 = f32 + packed Apk (h layout, N=1024)
template <int OUTMODE>
__global__ __launch_bounds__(256) void k_gemm(
    const u16* __restrict__ Ahi, const u16* __restrict__ Alo,
    const u16* __restrict__ Bhi, const u16* __restrict__ Blo,
    const float* __restrict__ bias,
    float* __restrict__ C, u16* __restrict__ Chi, u16* __restrict__ Clo,
    u16* __restrict__ Apk, int N, int K) {
  __shared__ __align__(16) u16 sAhi[128 * 64];
  __shared__ __align__(16) u16 sAlo[128 * 64];
  __shared__ __align__(16) u16 sBhi[128 * 64];
  __shared__ __align__(16) u16 sBlo[128 * 64];

  const int t = threadIdx.x;
  const int row0 = blockIdx.y * 128, col0 = blockIdx.x * 128;
  const int wave = t >> 6, lane = t & 63;
  const int w64 = wave * 64;
  const int wm = (wave & 1) * 64, wn = (wave >> 1) * 64;
  const int lm = lane & 15, lq = lane >> 4;
  const int pb = lm & 7;

  f32x4 acc[4][4] = {};

  int sm[4], skc[4], sub[4];
#pragma unroll
  for (int i = 0; i < 4; ++i) {
    const int u = i * 256 + t;
    sm[i] = u >> 3;
    skc[i] = (u & 7) ^ (sm[i] & 7);
    sub[i] = (i * 256 + w64) * 8;
  }

  const int nk = K >> 6;
  for (int kt = 0; kt < nk; ++kt) {
    const int k0 = kt << 6;
    __syncthreads();
#pragma unroll
    for (int i = 0; i < 4; ++i) {
      const size_t ga = (size_t)(row0 + sm[i]) * K + k0 + skc[i] * 8;
      const size_t gb = (size_t)(col0 + sm[i]) * K + k0 + skc[i] * 8;
      ld_lds16(Ahi + ga, &sAhi[sub[i]]);
      ld_lds16(Alo + ga, &sAlo[sub[i]]);
      ld_lds16(Bhi + gb, &sBhi[sub[i]]);
      ld_lds16(Blo + gb, &sBlo[sub[i]]);
    }
    __syncthreads();
#pragma unroll
    for (int kk = 0; kk < 2; ++kk) {
      const int pos = ((kk * 4 + lq) ^ pb) * 8;
      bf16x8 ah[4], al[4], bh[4], bl[4];
#pragma unroll
      for (int i = 0; i < 4; ++i) {
        const int ma = (wm + i * 16 + lm) * 64;
        const int mb = (wn + i * 16 + lm) * 64;
        ah[i] = *(const bf16x8*)&sAhi[ma + pos];
        al[i] = *(const bf16x8*)&sAlo[ma + pos];
        bh[i] = *(const bf16x8*)&sBhi[mb + pos];
        bl[i] = *(const bf16x8*)&sBlo[mb + pos];
      }
#pragma unroll
      for (int i = 0; i < 4; ++i)
#pragma unroll
        for (int j = 0; j < 4; ++j) {
          acc[i][j] = __builtin_amdgcn_mfma_f32_16x16x32_bf16(ah[i], bh[j], acc[i][j], 0, 0, 0);
          acc[i][j] = __builtin_amdgcn_mfma_f32_16x16x32_bf16(al[i], bh[j], acc[i][j], 0, 0, 0);
          acc[i][j] = __builtin_amdgcn_mfma_f32_16x16x32_bf16(ah[i], bl[j], acc[i][j], 0, 0, 0);
        }
    }
  }

#pragma unroll
  for (int i = 0; i < 4; ++i) {
    const int grow = row0 + wm + i * 16 + lq * 4;
#pragma unroll
    for (int j = 0; j < 4; ++j) {
      const int gcol = col0 + wn + j * 16 + lm;
      const float bs = bias ? bias[gcol] : 0.0f;
#pragma unroll
      for (int d = 0; d < 4; ++d) {
        const float v = acc[i][j][d] + bs;
        const size_t idx = (size_t)(grow + d) * N + gcol;
        C[idx] = v;
        if (OUTMODE == 1) {
          const float h = bf_val(v);
          Chi[idx] = bf_bits(v);
          Clo[idx] = bf_bits(v - h);
        }
        if (OUTMODE == 2) {
          pack_write(Apk, grow + d, gcol, v);
        }
      }
    }
  }
}

// ---------------- fused gh-GEMM + GRU gate kernel (v3: counted-vmcnt pipeline) ----------------
// 512 threads / 8 waves; tile 256(M) x 192(N'); BK=32 double-buffered (112 KB LDS, 1 blk/CU).
// Waves 4M x 2N, each owns 64x96 via 2x3 mfma_f32_32x32x16_bf16 frags (split-3: 36 MFMA/tile).
// Operands pre-packed (hi/lo interleaved + XOR swizzle baked into global layout) so
// global_load_lds staging is linear and ds_read_b128 is conflict-free.
// Schedule per K-tile: rd(s0) -> MFMA(s0) -> rd(s1) -> lgkm(0) -> bar ->
//   STAGE(kt+2) -> MFMA(s1) -> vmcnt(7) -> bar.  vmcnt never drains to 0 in-loop.

#define SZA (256 * 64)
#define SZB (192 * 64)
#define MF(a, b, c) c = __builtin_amdgcn_mfma_f32_32x32x16_bf16(a, b, c, 0, 0, 0)

__global__ __launch_bounds__(512, 2) void k_fused3(
    const u16* __restrict__ Apk,   // packed h splits [4096][2048]
    const u16* __restrict__ Bpk,   // packed Whh'     [3072][2048]
    const float* __restrict__ C0,  // [4096][3072] W'-order
    const float* __restrict__ token,
    const float* __restrict__ wtok,
    const float* __restrict__ b_hh,
    const float* __restrict__ h_in, float* __restrict__ h_out,
    u16* __restrict__ Apk_out) {
  __shared__ __align__(16) u16 sA[2 * SZA];
  __shared__ __align__(16) u16 sB[2 * SZB];

  const int t = threadIdx.x;
  const int wave = t >> 6, lane = t & 63;
  const int row0 = blockIdx.y * 256;
  const int colW0 = blockIdx.x * 192;
  const int wm = (wave >> 1) * 64;   // 0,0,64,64,128,128,192,192
  const int wn = (wave & 1) * 96;
  const int lr = lane & 31, lh = lane >> 5;
  const int pb7 = lr & 7;
  const int wb = wave * 512;         // staging LDS base (u16), +lane*8 by HW

  f32x16 acc[2][3] = {};

  // linear staging sources (swizzle baked into the packed global layout)
  const u16* agb = Apk + ((size_t)(row0 + (t >> 3)) << 11) + (t & 7) * 8;
  const u16* bgb = Bpk + ((size_t)(colW0 + (t >> 3)) << 11) + (t & 7) * 8;

#define STAGE(kt_, ab, bb)                                            \
  ld_lds16(agb + (kt_) * 64,          &sA[(ab) + wb]);                \
  ld_lds16(agb + (kt_) * 64 + 131072, &sA[(ab) + 4096 + wb]);         \
  ld_lds16(agb + (kt_) * 64 + 262144, &sA[(ab) + 8192 + wb]);         \
  ld_lds16(agb + (kt_) * 64 + 393216, &sA[(ab) + 12288 + wb]);        \
  ld_lds16(bgb + (kt_) * 64,          &sB[(bb) + wb]);                \
  ld_lds16(bgb + (kt_) * 64 + 131072, &sB[(bb) + 4096 + wb]);         \
  ld_lds16(bgb + (kt_) * 64 + 262144, &sB[(bb) + 8192 + wb]);

  // fragment read offsets (u16). Row r -> r*64; chunk slot p = c ^ (r&7), r&7 == lr&7.
  const int offA0 = (wm + lr) * 64, offA1 = offA0 + 2048;
  const int offB0 = (wn + lr) * 64, offB1 = offB0 + 2048, offB2 = offB0 + 4096;
  const int p0h = ((2 * lh) ^ pb7) * 8, p0l = ((2 * lh + 1) ^ pb7) * 8;
  const int p1h = ((4 + 2 * lh) ^ pb7) * 8, p1l = ((5 + 2 * lh) ^ pb7) * 8;

  STAGE(0, 0, 0);
  STAGE(1, SZA, SZB);
  asm volatile("s_waitcnt vmcnt(7)" ::: "memory");
  __builtin_amdgcn_s_barrier();

#define TILE_BODY(AB, BB, KT)                                                      \
  {                                                                                \
    bf16x8 a0h = *(const bf16x8*)&sA[(AB) + offA0 + p0h];                          \
    bf16x8 a0l = *(const bf16x8*)&sA[(AB) + offA0 + p0l];                          \
    bf16x8 a1h = *(const bf16x8*)&sA[(AB) + offA1 + p0h];                          \
    bf16x8 a1l = *(const bf16x8*)&sA[(AB) + offA1 + p0l];                          \
    bf16x8 b0h = *(const bf16x8*)&sB[(BB) + offB0 + p0h];                          \
    bf16x8 b0l = *(const bf16x8*)&sB[(BB) + offB0 + p0l];                          \
    bf16x8 b1h = *(const bf16x8*)&sB[(BB) + offB1 + p0h];                          \
    bf16x8 b1l = *(const bf16x8*)&sB[(BB) + offB1 + p0l];                          \
    bf16x8 b2h = *(const bf16x8*)&sB[(BB) + offB2 + p0h];                          \
    bf16x8 b2l = *(const bf16x8*)&sB[(BB) + offB2 + p0l];                          \
    __builtin_amdgcn_s_setprio(1);                                                 \
    MF(a0h, b0h, acc[0][0]); MF(a1h, b0h, acc[1][0]);                              \
    MF(a0h, b1h, acc[0][1]); MF(a1h, b1h, acc[1][1]);                              \
    MF(a0h, b2h, acc[0][2]); MF(a1h, b2h, acc[1][2]);                              \
    MF(a0l, b0h, acc[0][0]); MF(a1l, b0h, acc[1][0]);                              \
    MF(a0l, b1h, acc[0][1]); MF(a1l, b1h, acc[1][1]);                              \
    MF(a0l, b2h, acc[0][2]); MF(a1l, b2h, acc[1][2]);                              \
    MF(a0h, b0l, acc[0][0]); MF(a1h, b0l, acc[1][0]);                              \
    MF(a0h, b1l, acc[0][1]); MF(a1h, b1l, acc[1][1]);                              \
    MF(a0h, b2l, acc[0][2]); MF(a1h, b2l, acc[1][2]);                              \
    __builtin_amdgcn_s_setprio(0);                                                 \
    bf16x8 x0h = *(const bf16x8*)&sA[(AB) + offA0 + p1h];                          \
    bf16x8 x0l = *(const bf16x8*)&sA[(AB) + offA0 + p1l];                          \
    bf16x8 x1h = *(const bf16x8*)&sA[(AB) + offA1 + p1h];                          \
    bf16x8 x1l = *(const bf16x8*)&sA[(AB) + offA1 + p1l];                          \
    bf16x8 y0h = *(const bf16x8*)&sB[(BB) + offB0 + p1h];                          \
    bf16x8 y0l = *(const bf16x8*)&sB[(BB) + offB0 + p1l];                          \
    bf16x8 y1h = *(const bf16x8*)&sB[(BB) + offB1 + p1h];                          \
    bf16x8 y1l = *(const bf16x8*)&sB[(BB) + offB1 + p1l];                          \
    bf16x8 y2h = *(const bf16x8*)&sB[(BB) + offB2 + p1h];                          \
    bf16x8 y2l = *(const bf16x8*)&sB[(BB) + offB2 + p1l];                          \
    asm volatile("s_waitcnt lgkmcnt(0)" ::: "memory");                             \
    __builtin_amdgcn_sched_barrier(0);                                             \
    __builtin_amdgcn_s_barrier();                                                  \
    if ((KT) < 30) { STAGE((KT) + 2, AB, BB); }                                    \
    __builtin_amdgcn_s_setprio(1);                                                 \
    MF(x0h, y0h, acc[0][0]); MF(x1h, y0h, acc[1][0]);                              \
    MF(x0h, y1h, acc[0][1]); MF(x1h, y1h, acc[1][1]);                              \
    MF(x0h, y2h, acc[0][2]); MF(x1h, y2h, acc[1][2]);                              \
    MF(x0l, y0h, acc[0][0]); MF(x1l, y0h, acc[1][0]);                              \
    MF(x0l, y1h, acc[0][1]); MF(x1l, y1h, acc[1][1]);                              \
    MF(x0l, y2h, acc[0][2]); MF(x1l, y2h, acc[1][2]);                              \
    MF(x0h, y0l, acc[0][0]); MF(x1h, y0l, acc[1][0]);                              \
    MF(x0h, y1l, acc[0][1]); MF(x1h, y1l, acc[1][1]);                              \
    MF(x0h, y2l, acc[0][2]); MF(x1h, y2l, acc[1][2]);                              \
    __builtin_amdgcn_s_setprio(0);                                                 \
    if ((KT) < 30) { asm volatile("s_waitcnt vmcnt(7)" ::: "memory"); }            \
    else           { asm volatile("s_waitcnt vmcnt(0)" ::: "memory"); }            \
    __builtin_amdgcn_s_barrier();                                                  \
  }

#pragma unroll 1
  for (int kt = 0; kt < 32; kt += 2) {
    TILE_BODY(0, 0, kt);
    TILE_BODY(SZA, SZB, kt + 1);
  }
#undef TILE_BODY
#undef STAGE

  // ---- fused GRU epilogue (exact f32) ----
  // Lane owns h-col c; frags j=0,1,2 are r/u/n gates for that col (96 = 3x32 interleave).
  const int w0 = colW0 + wn + lr;                  // W'-row of r-gate
  const int c = ((colW0 + wn) / 96) * 32 + lr;     // h-col
  float wt[3][3];
#pragma unroll
  for (int j = 0; j < 3; ++j) {
    wt[j][0] = wtok[(w0 + j * 32) * 3 + 0];
    wt[j][1] = wtok[(w0 + j * 32) * 3 + 1];
    wt[j][2] = wtok[(w0 + j * 32) * 3 + 2];
  }
  const float bn = b_hh[2048 + c];
  const int ktc = c >> 5, kc2 = (c >> 3) & 3, ec = c & 7;
#pragma unroll
  for (int mi = 0; mi < 2; ++mi) {
#pragma unroll
    for (int d = 0; d < 16; ++d) {
      const int row = row0 + wm + mi * 32 + 4 * lh + (d & 3) + 8 * (d >> 2);
      const float4 tk = *(const float4*)&token[row * 4];
      const size_t cb = (size_t)row * NP;
      const float pr = C0[cb + w0]      + acc[mi][0][d] + tk.x * wt[0][0] + tk.y * wt[0][1] + tk.z * wt[0][2];
      const float pu = C0[cb + w0 + 32] + acc[mi][1][d] + tk.x * wt[1][0] + tk.y * wt[1][1] + tk.z * wt[1][2];
      const float pn = C0[cb + w0 + 64] + tk.x * wt[2][0] + tk.y * wt[2][1] + tk.z * wt[2][2];
      const float hn = acc[mi][2][d] + bn;
      const float r = 1.0f / (1.0f + expf(-pr));
      const float u = 1.0f / (1.0f + expf(-pu));
      const float n = tanhf(pn + r * hn);
      const size_t hidx = (size_t)row * HIDN + c;
      const float hv = (1.0f - u) * n + u * h_in[hidx];
      h_out[hidx] = hv;
      const size_t pbase = ((size_t)row << 11) + ktc * 64;
      const int rx = row & 7;
      const float hh = bf_val(hv);
      Apk_out[pbase + (((kc2 << 1) ^ rx) << 3) + ec] = bf_bits(hv);
      Apk_out[pbase + ((((kc2 << 1) | 1) ^ rx) << 3) + ec] = bf_bits(hv - hh);
    }
  }
}
#undef MF

// ---------------- per-step output kernel ----------------
__global__ __launch_bounds__(256) void k_out(
    const float* __restrict__ h, const float* __restrict__ W_out,
    const float* __restrict__ b_out,
    float* __restrict__ out, float* __restrict__ token, int step) {
  const int wave = threadIdx.x >> 6, lane = threadIdx.x & 63;
  const int row = blockIdx.x * 4 + wave;
  const float4* hp = (const float4*)(h + (size_t)row * 1024);
  const float4* w0p = (const float4*)(W_out);
  const float4* w1p = (const float4*)(W_out + 1024);
  const float4* w2p = (const float4*)(W_out + 2048);
  float s0 = 0.f, s1 = 0.f, s2 = 0.f;
#pragma unroll
  for (int c = 0; c < 4; ++c) {
    const int k = lane + 64 * c;
    const float4 hv = hp[k];
    const float4 a = w0p[k], bq = w1p[k], cq = w2p[k];
    s0 += hv.x * a.x + hv.y * a.y + hv.z * a.z + hv.w * a.w;
    s1 += hv.x * bq.x + hv.y * bq.y + hv.z * bq.z + hv.w * bq.w;
    s2 += hv.x * cq.x + hv.y * cq.y + hv.z * cq.z + hv.w * cq.w;
  }
#pragma unroll
  for (int off = 32; off > 0; off >>= 1) {
    s0 += __shfl_xor(s0, off, 64);
    s1 += __shfl_xor(s1, off, 64);
    s2 += __shfl_xor(s2, off, 64);
  }
  if (lane == 0) {
    const float o0 = s0 + b_out[0];
    const float o1 = s1 + b_out[1];
    const float o2 = s2 + b_out[2];
    const float bass = 1.0f / (1.0f + expf(-o0));
    const float rhy = 1.0f / (1.0f + expf(-o2));
    const size_t ob = ((size_t)row * NST + step) * 3;
    out[ob + 0] = bass;
    out[ob + 1] = o1;
    out[ob + 2] = rhy;
    token[row * 4 + 0] = bass;
    token[row * 4 + 1] = o1;
    token[row * 4 + 2] = (rhy > 0.5f) ? 1.0f : 0.0f;
  }
}

// ---------------- host ----------------
extern "C" void kernel_launch(void* const* d_in, const int* in_sizes, int n_in,
                              void* d_out, int out_size, void* d_ws, size_t ws_size,
                              hipStream_t stream) {
  const float* z = (const float*)d_in[0];
  const float* W_zh = (const float*)d_in[3];
  const float* b_zh = (const float*)d_in[4];
  const float* W_zi = (const float*)d_in[5];
  const float* b_zi = (const float*)d_in[6];
  const float* W_ih = (const float*)d_in[7];
  const float* b_ih = (const float*)d_in[8];
  const float* W_hh = (const float*)d_in[9];
  const float* b_hh = (const float*)d_in[10];
  const float* W_out = (const float*)d_in[11];
  const float* b_out = (const float*)d_in[12];
  const float* init_input = (const float*)d_in[13];
  float* out = (float*)d_out;

  char* p = (char*)d_ws;
  auto alloc = [&](size_t bytes) {
    char* q = p;
    p += (bytes + 255) & ~(size_t)255;
    return q;
  };
  float* h[2];
  u16* Apk[2];
  for (int s = 0; s < 2; ++s) {
    h[s] = (float*)alloc((size_t)BS * HIDN * 4);
    Apk[s] = (u16*)alloc((size_t)BS * 2048 * 2);
  }
  float* C0 = (float*)alloc((size_t)BS * NP * 4);
  u16* z_hi = (u16*)alloc((size_t)BS * ZD * 2);
  u16* z_lo = (u16*)alloc((size_t)BS * ZD * 2);
  float* zin = (float*)alloc((size_t)BS * ZINN * 4);
  u16* zin_hi = (u16*)alloc((size_t)BS * ZINN * 2);
  u16* zin_lo = (u16*)alloc((size_t)BS * ZINN * 2);
  u16* Wzh_hi = (u16*)alloc((size_t)HIDN * ZD * 2);
  u16* Wzh_lo = (u16*)alloc((size_t)HIDN * ZD * 2);
  u16* Wzi_hi = (u16*)alloc((size_t)ZINN * ZD * 2);
  u16* Wzi_lo = (u16*)alloc((size_t)ZINN * ZD * 2);
  u16* Wihz_hi = (u16*)alloc((size_t)NP * ZINN * 2);
  u16* Wihz_lo = (u16*)alloc((size_t)NP * ZINN * 2);
  u16* Bpk = (u16*)alloc((size_t)NP * 2048 * 2);
  float* wtok = (float*)alloc((size_t)NP * 3 * 4);
  float* cb0 = (float*)alloc((size_t)NP * 4);
  float* token = (float*)alloc((size_t)BS * 4 * 4);

  // ---- prep ----
  k_pack_whh<<<dim3((NP * HIDN + 255) / 256), 256, 0, stream>>>(W_hh, Bpk);
  k_split<<<dim3((HIDN * ZD + 255) / 256), 256, 0, stream>>>(W_zh, Wzh_hi, Wzh_lo, HIDN * ZD);
  k_split<<<dim3((ZINN * ZD + 255) / 256), 256, 0, stream>>>(W_zi, Wzi_hi, Wzi_lo, ZINN * ZD);
  k_split<<<dim3((BS * ZD + 255) / 256), 256, 0, stream>>>(z, z_hi, z_lo, BS * ZD);
  k_prep_wih<<<dim3((NP * 128 + 255) / 256), 256, 0, stream>>>(W_ih, b_ih, b_hh, Wihz_hi, Wihz_lo, wtok, cb0);
  k_token_init<<<dim3((BS * 4 + 255) / 256), 256, 0, stream>>>(init_input, token);

  // ---- prep GEMMs ----
  k_gemm<2><<<dim3(HIDN / 128, BS / 128), 256, 0, stream>>>(
      z_hi, z_lo, Wzh_hi, Wzh_lo, b_zh, h[0], nullptr, nullptr, Apk[0], HIDN, ZD);
  k_gemm<1><<<dim3(ZINN / 128, BS / 128), 256, 0, stream>>>(
      z_hi, z_lo, Wzi_hi, Wzi_lo, b_zi, zin, zin_hi, zin_lo, nullptr, ZINN, ZD);
  k_gemm<0><<<dim3(NP / 128, BS / 128), 256, 0, stream>>>(
      zin_hi, zin_lo, Wihz_hi, Wihz_lo, cb0, C0, nullptr, nullptr, nullptr, NP, ZINN);

  // ---- 32 recurrent steps ----
  for (int t = 0; t < NST; ++t) {
    const int cur = t & 1, nxt = (t + 1) & 1;
    k_fused3<<<dim3(NP / 192, BS / 256), 512, 0, stream>>>(
        Apk[cur], Bpk, C0, token, wtok, b_hh, h[cur], h[nxt], Apk[nxt]);
    k_out<<<dim3(BS / 4), 256, 0, stream>>>(h[nxt], W_out, b_out, out, token, t);
  }
  (void)in_sizes; (void)n_in; (void)out_size; (void)ws_size;
}

// Round 3
// 2854.244 us; speedup vs baseline: 1.0246x; 1.0246x over previous
//
#include <hip/hip_runtime.h>
#include <hip/hip_bf16.h>
#include <math.h>

#define BS   4096
#define ZD   512
#define HIDN 1024
#define ZINN 128
#define NST  32
#define NP   3072   // 3*HIDN, gate-interleaved column space (96 = 3x32 groups)

typedef unsigned short u16;
typedef __bf16 bf16x8 __attribute__((ext_vector_type(8)));
typedef float f32x4 __attribute__((ext_vector_type(4)));
typedef float f32x16 __attribute__((ext_vector_type(16)));

static __device__ __forceinline__ u16 bf_bits(float v) {
  __bf16 b = (__bf16)v;
  return __builtin_bit_cast(unsigned short, b);
}
static __device__ __forceinline__ float bf_val(float v) {
  return (float)(__bf16)v;
}

// async global -> LDS, 16 bytes per lane. LDS dest = wave-uniform base + lane*16.
static __device__ __forceinline__ void ld_lds16(const u16* g, u16* l) {
  __builtin_amdgcn_global_load_lds(
      (const __attribute__((address_space(1))) void*)g,
      (__attribute__((address_space(3))) void*)l, 16, 0, 0);
}

// W' row w -> original W_hh/W_ih row. 32-granular interleave for 32x32 MFMA:
// w = g*96 + j*32 + m  ->  j*1024 + g*32 + m   (j = gate r/u/n, m = h-col within group)
static __device__ __forceinline__ int r_orig(int w) {
  const int g = w / 96;
  const int rem = w - g * 96;
  const int j = rem >> 5, m = rem & 31;
  return j * 1024 + g * 32 + m;
}

// ---------------- packed split layout ----------------
// Pk[row][2048 u16]: 32 K-tiles x 64 u16. Within tile: 8 chunks of 8 u16;
// chunk c = 2*kc + islo (kc = (k>>3)&3) stored at slot p = c ^ (row&7).
// -> staging is LINEAR global_load_lds; ds_read_b128 is bank-conflict-free.
static __device__ __forceinline__ void pack_write(u16* __restrict__ P, int row, int col, float v) {
  const int kt = col >> 5, kc = (col >> 3) & 3, e = col & 7, rx = row & 7;
  const size_t base = ((size_t)row << 11) + kt * 64;
  const float h = bf_val(v);
  P[base + (((kc << 1) ^ rx) << 3) + e] = bf_bits(v);
  P[base + ((((kc << 1) | 1) ^ rx) << 3) + e] = bf_bits(v - h);
}

// ---------------- prep kernels ----------------

__global__ void k_split(const float* __restrict__ s, u16* __restrict__ hi,
                        u16* __restrict__ lo, int n) {
  int i = blockIdx.x * 256 + threadIdx.x;
  if (i >= n) return;
  float v = s[i];
  float h = bf_val(v);
  hi[i] = bf_bits(v);
  lo[i] = bf_bits(v - h);
}

// W_hh -> packed/swizzled Bpk with gate-interleaved row reorder
__global__ void k_pack_whh(const float* __restrict__ W_hh, u16* __restrict__ Bpk) {
  int i = blockIdx.x * 256 + threadIdx.x;
  if (i >= NP * HIDN) return;
  const int w = i >> 10, k = i & 1023;
  const float v = W_hh[(size_t)r_orig(w) * HIDN + k];
  pack_write(Bpk, w, k, v);
}

// W_ih[:,3:131] -> split (reordered rows); W_ih[:,0:3] -> wtok (reordered); cb0 (reordered)
__global__ void k_prep_wih(const float* __restrict__ W_ih, const float* __restrict__ b_ih,
                           const float* __restrict__ b_hh,
                           u16* __restrict__ whi, u16* __restrict__ wlo,
                           float* __restrict__ wtok, float* __restrict__ cb0) {
  int i = blockIdx.x * 256 + threadIdx.x;
  if (i < NP * 128) {
    const int w = i >> 7, c = i & 127;
    const int r = r_orig(w);
    const float v = W_ih[r * 131 + 3 + c];
    const float h = bf_val(v);
    whi[i] = bf_bits(v);
    wlo[i] = bf_bits(v - h);
  }
  if (i < NP * 3) {
    const int w = i / 3, s = i - w * 3;
    wtok[i] = W_ih[r_orig(w) * 131 + s];
  }
  if (i < NP) {
    const int r = r_orig(i);
    cb0[i] = b_ih[r] + (r < 2048 ? b_hh[r] : 0.0f);
  }
}

__global__ void k_token_init(const float* __restrict__ init_input, float* __restrict__ token) {
  int i = blockIdx.x * 256 + threadIdx.x;
  if (i < BS * 4) token[i] = ((i & 3) < 3) ? init_input[i & 3] : 0.0f;
}

// ---------------- generic split-3 GEMM (prep only): C = A*B^T (+bias) ----------------
// OUTMODE: 0 = f32 only, 1 = f32 + plain hi/lo splits, 2 = f32 + packed Apk (h layout, N=1024)
template <int OUTMODE>
__global__ __launch_bounds__(256) void k_gemm(
    const u16* __restrict__ Ahi, const u16* __restrict__ Alo,
    const u16* __restrict__ Bhi, const u16* __restrict__ Blo,
    const float* __restrict__ bias,
    float* __restrict__ C, u16* __restrict__ Chi, u16* __restrict__ Clo,
    u16* __restrict__ Apk, int N, int K) {
  __shared__ __align__(16) u16 sAhi[128 * 64];
  __shared__ __align__(16) u16 sAlo[128 * 64];
  __shared__ __align__(16) u16 sBhi[128 * 64];
  __shared__ __align__(16) u16 sBlo[128 * 64];

  const int t = threadIdx.x;
  const int row0 = blockIdx.y * 128, col0 = blockIdx.x * 128;
  const int wave = t >> 6, lane = t & 63;
  const int w64 = wave * 64;
  const int wm = (wave & 1) * 64, wn = (wave >> 1) * 64;
  const int lm = lane & 15, lq = lane >> 4;
  const int pb = lm & 7;

  f32x4 acc[4][4] = {};

  int sm[4], skc[4], sub[4];
#pragma unroll
  for (int i = 0; i < 4; ++i) {
    const int u = i * 256 + t;
    sm[i] = u >> 3;
    skc[i] = (u & 7) ^ (sm[i] & 7);
    sub[i] = (i * 256 + w64) * 8;
  }

  const int nk = K >> 6;
  for (int kt = 0; kt < nk; ++kt) {
    const int k0 = kt << 6;
    __syncthreads();
#pragma unroll
    for (int i = 0; i < 4; ++i) {
      const size_t ga = (size_t)(row0 + sm[i]) * K + k0 + skc[i] * 8;
      const size_t gb = (size_t)(col0 + sm[i]) * K + k0 + skc[i] * 8;
      ld_lds16(Ahi + ga, &sAhi[sub[i]]);
      ld_lds16(Alo + ga, &sAlo[sub[i]]);
      ld_lds16(Bhi + gb, &sBhi[sub[i]]);
      ld_lds16(Blo + gb, &sBlo[sub[i]]);
    }
    __syncthreads();
#pragma unroll
    for (int kk = 0; kk < 2; ++kk) {
      const int pos = ((kk * 4 + lq) ^ pb) * 8;
      bf16x8 ah[4], al[4], bh[4], bl[4];
#pragma unroll
      for (int i = 0; i < 4; ++i) {
        const int ma = (wm + i * 16 + lm) * 64;
        const int mb = (wn + i * 16 + lm) * 64;
        ah[i] = *(const bf16x8*)&sAhi[ma + pos];
        al[i] = *(const bf16x8*)&sAlo[ma + pos];
        bh[i] = *(const bf16x8*)&sBhi[mb + pos];
        bl[i] = *(const bf16x8*)&sBlo[mb + pos];
      }
#pragma unroll
      for (int i = 0; i < 4; ++i)
#pragma unroll
        for (int j = 0; j < 4; ++j) {
          acc[i][j] = __builtin_amdgcn_mfma_f32_16x16x32_bf16(ah[i], bh[j], acc[i][j], 0, 0, 0);
          acc[i][j] = __builtin_amdgcn_mfma_f32_16x16x32_bf16(al[i], bh[j], acc[i][j], 0, 0, 0);
          acc[i][j] = __builtin_amdgcn_mfma_f32_16x16x32_bf16(ah[i], bl[j], acc[i][j], 0, 0, 0);
        }
    }
  }

#pragma unroll
  for (int i = 0; i < 4; ++i) {
    const int grow = row0 + wm + i * 16 + lq * 4;
#pragma unroll
    for (int j = 0; j < 4; ++j) {
      const int gcol = col0 + wn + j * 16 + lm;
      const float bs = bias ? bias[gcol] : 0.0f;
#pragma unroll
      for (int d = 0; d < 4; ++d) {
        const float v = acc[i][j][d] + bs;
        const size_t idx = (size_t)(grow + d) * N + gcol;
        C[idx] = v;
        if (OUTMODE == 1) {
          const float h = bf_val(v);
          Chi[idx] = bf_bits(v);
          Clo[idx] = bf_bits(v - h);
        }
        if (OUTMODE == 2) {
          pack_write(Apk, grow + d, gcol, v);
        }
      }
    }
  }
}

// ---------------- fused gh-GEMM + GRU gate kernel (v4: register read-ahead) ----------------
// 512 threads / 8 waves; tile 256(M) x 192(N'); BK=32 double-buffered (112 KB LDS, 1 blk/CU).
// Waves 4M x 2N, each owns 64x96 via 2x3 mfma_f32_32x32x16_bf16 frags (split-3: 36 MFMA/tile).
// ds_reads for phase p+1 are issued BEFORE the MFMA cluster of phase p (register X/Y
// double-buffer), no hand waits / sched pins — the compiler interleaves the 10 reads into
// the 18-MFMA shadow with fine-grained lgkmcnt. ONE __syncthreads per K-tile handles both
// residency (stage loads get a full-body shadow) and the LDS write-after-read hazard.

#define SZA (256 * 64)
#define SZB (192 * 64)
#define MF(a, b, c) c = __builtin_amdgcn_mfma_f32_32x32x16_bf16(a, b, c, 0, 0, 0)

__global__ __launch_bounds__(512, 2) void k_fused3(
    const u16* __restrict__ Apk,   // packed h splits [4096][2048]
    const u16* __restrict__ Bpk,   // packed Whh'     [3072][2048]
    const float* __restrict__ C0,  // [4096][3072] W'-order
    const float* __restrict__ token,
    const float* __restrict__ wtok,
    const float* __restrict__ b_hh,
    const float* __restrict__ h_in, float* __restrict__ h_out,
    u16* __restrict__ Apk_out) {
  __shared__ __align__(16) u16 sA[2 * SZA];
  __shared__ __align__(16) u16 sB[2 * SZB];

  const int t = threadIdx.x;
  const int wave = t >> 6, lane = t & 63;
  const int row0 = blockIdx.y * 256;
  const int colW0 = blockIdx.x * 192;
  const int wm = (wave >> 1) * 64;   // 0,0,64,64,128,128,192,192
  const int wn = (wave & 1) * 96;
  const int lr = lane & 31, lh = lane >> 5;
  const int pb7 = lr & 7;
  const int wb = wave * 512;         // staging LDS base (u16), +lane*8 by HW

  f32x16 acc[2][3] = {};

  // linear staging sources (swizzle baked into the packed global layout)
  const u16* agb = Apk + ((size_t)(row0 + (t >> 3)) << 11) + (t & 7) * 8;
  const u16* bgb = Bpk + ((size_t)(colW0 + (t >> 3)) << 11) + (t & 7) * 8;

#define STAGE(kt_, ab, bb)                                            \
  ld_lds16(agb + (kt_) * 64,          &sA[(ab) + wb]);                \
  ld_lds16(agb + (kt_) * 64 + 131072, &sA[(ab) + 4096 + wb]);         \
  ld_lds16(agb + (kt_) * 64 + 262144, &sA[(ab) + 8192 + wb]);         \
  ld_lds16(agb + (kt_) * 64 + 393216, &sA[(ab) + 12288 + wb]);        \
  ld_lds16(bgb + (kt_) * 64,          &sB[(bb) + wb]);                \
  ld_lds16(bgb + (kt_) * 64 + 131072, &sB[(bb) + 4096 + wb]);         \
  ld_lds16(bgb + (kt_) * 64 + 262144, &sB[(bb) + 8192 + wb]);

  // fragment read offsets (u16). Row r -> r*64; chunk slot p = c ^ (r&7), r&7 == lr&7.
  const int offA0 = (wm + lr) * 64, offA1 = offA0 + 2048;
  const int offB0 = (wn + lr) * 64, offB1 = offB0 + 2048, offB2 = offB0 + 4096;
  const int p0h = ((2 * lh) ^ pb7) * 8, p0l = ((2 * lh + 1) ^ pb7) * 8;
  const int p1h = ((4 + 2 * lh) ^ pb7) * 8, p1l = ((5 + 2 * lh) ^ pb7) * 8;

  bf16x8 Xa0h, Xa0l, Xa1h, Xa1l, Xb0h, Xb0l, Xb1h, Xb1l, Xb2h, Xb2l;
  bf16x8 Ya0h, Ya0l, Ya1h, Ya1l, Yb0h, Yb0l, Yb1h, Yb1l, Yb2h, Yb2l;

#define RD(P, AB, BB, PH, PL)                                 \
  P##a0h = *(const bf16x8*)&sA[(AB) + offA0 + (PH)];          \
  P##a0l = *(const bf16x8*)&sA[(AB) + offA0 + (PL)];          \
  P##a1h = *(const bf16x8*)&sA[(AB) + offA1 + (PH)];          \
  P##a1l = *(const bf16x8*)&sA[(AB) + offA1 + (PL)];          \
  P##b0h = *(const bf16x8*)&sB[(BB) + offB0 + (PH)];          \
  P##b0l = *(const bf16x8*)&sB[(BB) + offB0 + (PL)];          \
  P##b1h = *(const bf16x8*)&sB[(BB) + offB1 + (PH)];          \
  P##b1l = *(const bf16x8*)&sB[(BB) + offB1 + (PL)];          \
  P##b2h = *(const bf16x8*)&sB[(BB) + offB2 + (PH)];          \
  P##b2l = *(const bf16x8*)&sB[(BB) + offB2 + (PL)];

#define MM(P)                                                    \
  MF(P##a0h, P##b0h, acc[0][0]); MF(P##a1h, P##b0h, acc[1][0]);  \
  MF(P##a0h, P##b1h, acc[0][1]); MF(P##a1h, P##b1h, acc[1][1]);  \
  MF(P##a0h, P##b2h, acc[0][2]); MF(P##a1h, P##b2h, acc[1][2]);  \
  MF(P##a0l, P##b0h, acc[0][0]); MF(P##a1l, P##b0h, acc[1][0]);  \
  MF(P##a0l, P##b1h, acc[0][1]); MF(P##a1l, P##b1h, acc[1][1]);  \
  MF(P##a0l, P##b2h, acc[0][2]); MF(P##a1l, P##b2h, acc[1][2]);  \
  MF(P##a0h, P##b0l, acc[0][0]); MF(P##a1h, P##b0l, acc[1][0]);  \
  MF(P##a0h, P##b1l, acc[0][1]); MF(P##a1h, P##b1l, acc[1][1]);  \
  MF(P##a0h, P##b2l, acc[0][2]); MF(P##a1h, P##b2l, acc[1][2]);

  // ---- prologue: fill both buffers, read first phase ----
  STAGE(0, 0, 0);
  STAGE(1, SZA, SZB);
  __syncthreads();
  RD(X, 0, 0, p0h, p0l);

  // ---- main loop: tile even -> buf0, odd -> buf1; one barrier per tile ----
#pragma unroll 1
  for (int kt = 0; kt < 32; kt += 2) {
    // body A: tile kt in buf0
    RD(Y, 0, 0, p1h, p1l);          // phase-1 reads, interleave under MFMA(X)
    MM(X);
    __syncthreads();                 // all reads of buf0 done; stage(kt+1) drained
    if (kt < 30) { STAGE(kt + 2, 0, 0); }
    RD(X, SZA, SZB, p0h, p0l);      // phase-0 of tile kt+1 (buf1), under MFMA(Y)
    MM(Y);
    // body B: tile kt+1 in buf1
    RD(Y, SZA, SZB, p1h, p1l);
    MM(X);
    __syncthreads();
    if (kt < 30) {
      STAGE(kt + 3, SZA, SZB);
      RD(X, 0, 0, p0h, p0l);        // phase-0 of tile kt+2 (buf0)
    }
    MM(Y);
  }
#undef RD
#undef MM
#undef STAGE

  // ---- fused GRU epilogue (exact f32) ----
  // Lane owns h-col c; frags j=0,1,2 are r/u/n gates for that col (96 = 3x32 interleave).
  const int w0 = colW0 + wn + lr;                  // W'-row of r-gate
  const int c = ((colW0 + wn) / 96) * 32 + lr;     // h-col
  float wt[3][3];
#pragma unroll
  for (int j = 0; j < 3; ++j) {
    wt[j][0] = wtok[(w0 + j * 32) * 3 + 0];
    wt[j][1] = wtok[(w0 + j * 32) * 3 + 1];
    wt[j][2] = wtok[(w0 + j * 32) * 3 + 2];
  }
  const float bn = b_hh[2048 + c];
  const int ktc = c >> 5, kc2 = (c >> 3) & 3, ec = c & 7;
#pragma unroll
  for (int mi = 0; mi < 2; ++mi) {
#pragma unroll
    for (int d = 0; d < 16; ++d) {
      const int row = row0 + wm + mi * 32 + 4 * lh + (d & 3) + 8 * (d >> 2);
      const float4 tk = *(const float4*)&token[row * 4];
      const size_t cb = (size_t)row * NP;
      const float pr = C0[cb + w0]      + acc[mi][0][d] + tk.x * wt[0][0] + tk.y * wt[0][1] + tk.z * wt[0][2];
      const float pu = C0[cb + w0 + 32] + acc[mi][1][d] + tk.x * wt[1][0] + tk.y * wt[1][1] + tk.z * wt[1][2];
      const float pn = C0[cb + w0 + 64] + tk.x * wt[2][0] + tk.y * wt[2][1] + tk.z * wt[2][2];
      const float hn = acc[mi][2][d] + bn;
      const float r = 1.0f / (1.0f + expf(-pr));
      const float u = 1.0f / (1.0f + expf(-pu));
      const float n = tanhf(pn + r * hn);
      const size_t hidx = (size_t)row * HIDN + c;
      const float hv = (1.0f - u) * n + u * h_in[hidx];
      h_out[hidx] = hv;
      const size_t pbase = ((size_t)row << 11) + ktc * 64;
      const int rx = row & 7;
      const float hh = bf_val(hv);
      Apk_out[pbase + (((kc2 << 1) ^ rx) << 3) + ec] = bf_bits(hv);
      Apk_out[pbase + ((((kc2 << 1) | 1) ^ rx) << 3) + ec] = bf_bits(hv - hh);
    }
  }
}
#undef MF

// ---------------- per-step output kernel ----------------
__global__ __launch_bounds__(256) void k_out(
    const float* __restrict__ h, const float* __restrict__ W_out,
    const float* __restrict__ b_out,
    float* __restrict__ out, float* __restrict__ token, int step) {
  const int wave = threadIdx.x >> 6, lane = threadIdx.x & 63;
  const int row = blockIdx.x * 4 + wave;
  const float4* hp = (const float4*)(h + (size_t)row * 1024);
  const float4* w0p = (const float4*)(W_out);
  const float4* w1p = (const float4*)(W_out + 1024);
  const float4* w2p = (const float4*)(W_out + 2048);
  float s0 = 0.f, s1 = 0.f, s2 = 0.f;
#pragma unroll
  for (int c = 0; c < 4; ++c) {
    const int k = lane + 64 * c;
    const float4 hv = hp[k];
    const float4 a = w0p[k], bq = w1p[k], cq = w2p[k];
    s0 += hv.x * a.x + hv.y * a.y + hv.z * a.z + hv.w * a.w;
    s1 += hv.x * bq.x + hv.y * bq.y + hv.z * bq.z + hv.w * bq.w;
    s2 += hv.x * cq.x + hv.y * cq.y + hv.z * cq.z + hv.w * cq.w;
  }
#pragma unroll
  for (int off = 32; off > 0; off >>= 1) {
    s0 += __shfl_xor(s0, off, 64);
    s1 += __shfl_xor(s1, off, 64);
    s2 += __shfl_xor(s2, off, 64);
  }
  if (lane == 0) {
    const float o0 = s0 + b_out[0];
    const float o1 = s1 + b_out[1];
    const float o2 = s2 + b_out[2];
    const float bass = 1.0f / (1.0f + expf(-o0));
    const float rhy = 1.0f / (1.0f + expf(-o2));
    const size_t ob = ((size_t)row * NST + step) * 3;
    out[ob + 0] = bass;
    out[ob + 1] = o1;
    out[ob + 2] = rhy;
    token[row * 4 + 0] = bass;
    token[row * 4 + 1] = o1;
    token[row * 4 + 2] = (rhy > 0.5f) ? 1.0f : 0.0f;
  }
}

// ---------------- host ----------------
extern "C" void kernel_launch(void* const* d_in, const int* in_sizes, int n_in,
                              void* d_out, int out_size, void* d_ws, size_t ws_size,
                              hipStream_t stream) {
  const float* z = (const float*)d_in[0];
  const float* W_zh = (const float*)d_in[3];
  const float* b_zh = (const float*)d_in[4];
  const float* W_zi = (const float*)d_in[5];
  const float* b_zi = (const float*)d_in[6];
  const float* W_ih = (const float*)d_in[7];
  const float* b_ih = (const float*)d_in[8];
  const float* W_hh = (const float*)d_in[9];
  const float* b_hh = (const float*)d_in[10];
  const float* W_out = (const float*)d_in[11];
  const float* b_out = (const float*)d_in[12];
  const float* init_input = (const float*)d_in[13];
  float* out = (float*)d_out;

  char* p = (char*)d_ws;
  auto alloc = [&](size_t bytes) {
    char* q = p;
    p += (bytes + 255) & ~(size_t)255;
    return q;
  };
  float* h[2];
  u16* Apk[2];
  for (int s = 0; s < 2; ++s) {
    h[s] = (float*)alloc((size_t)BS * HIDN * 4);
    Apk[s] = (u16*)alloc((size_t)BS * 2048 * 2);
  }
  float* C0 = (float*)alloc((size_t)BS * NP * 4);
  u16* z_hi = (u16*)alloc((size_t)BS * ZD * 2);
  u16* z_lo = (u16*)alloc((size_t)BS * ZD * 2);
  float* zin = (float*)alloc((size_t)BS * ZINN * 4);
  u16* zin_hi = (u16*)alloc((size_t)BS * ZINN * 2);
  u16* zin_lo = (u16*)alloc((size_t)BS * ZINN * 2);
  u16* Wzh_hi = (u16*)alloc((size_t)HIDN * ZD * 2);
  u16* Wzh_lo = (u16*)alloc((size_t)HIDN * ZD * 2);
  u16* Wzi_hi = (u16*)alloc((size_t)ZINN * ZD * 2);
  u16* Wzi_lo = (u16*)alloc((size_t)ZINN * ZD * 2);
  u16* Wihz_hi = (u16*)alloc((size_t)NP * ZINN * 2);
  u16* Wihz_lo = (u16*)alloc((size_t)NP * ZINN * 2);
  u16* Bpk = (u16*)alloc((size_t)NP * 2048 * 2);
  float* wtok = (float*)alloc((size_t)NP * 3 * 4);
  float* cb0 = (float*)alloc((size_t)NP * 4);
  float* token = (float*)alloc((size_t)BS * 4 * 4);

  // ---- prep ----
  k_pack_whh<<<dim3((NP * HIDN + 255) / 256), 256, 0, stream>>>(W_hh, Bpk);
  k_split<<<dim3((HIDN * ZD + 255) / 256), 256, 0, stream>>>(W_zh, Wzh_hi, Wzh_lo, HIDN * ZD);
  k_split<<<dim3((ZINN * ZD + 255) / 256), 256, 0, stream>>>(W_zi, Wzi_hi, Wzi_lo, ZINN * ZD);
  k_split<<<dim3((BS * ZD + 255) / 256), 256, 0, stream>>>(z, z_hi, z_lo, BS * ZD);
  k_prep_wih<<<dim3((NP * 128 + 255) / 256), 256, 0, stream>>>(W_ih, b_ih, b_hh, Wihz_hi, Wihz_lo, wtok, cb0);
  k_token_init<<<dim3((BS * 4 + 255) / 256), 256, 0, stream>>>(init_input, token);

  // ---- prep GEMMs ----
  k_gemm<2><<<dim3(HIDN / 128, BS / 128), 256, 0, stream>>>(
      z_hi, z_lo, Wzh_hi, Wzh_lo, b_zh, h[0], nullptr, nullptr, Apk[0], HIDN, ZD);
  k_gemm<1><<<dim3(ZINN / 128, BS / 128), 256, 0, stream>>>(
      z_hi, z_lo, Wzi_hi, Wzi_lo, b_zi, zin, zin_hi, zin_lo, nullptr, ZINN, ZD);
  k_gemm<0><<<dim3(NP / 128, BS / 128), 256, 0, stream>>>(
      zin_hi, zin_lo, Wihz_hi, Wihz_lo, cb0, C0, nullptr, nullptr, nullptr, NP, ZINN);

  // ---- 32 recurrent steps ----
  for (int t = 0; t < NST; ++t) {
    const int cur = t & 1, nxt = (t + 1) & 1;
    k_fused3<<<dim3(NP / 192, BS / 256), 512, 0, stream>>>(
        Apk[cur], Bpk, C0, token, wtok, b_hh, h[cur], h[nxt], Apk[nxt]);
    k_out<<<dim3(BS / 4), 256, 0, stream>>>(h[nxt], W_out, b_out, out, token, t);
  }
  (void)in_sizes; (void)n_in; (void)out_size; (void)ws_size;
}